// Round 1
// baseline (821.370 us; speedup 1.0000x reference)
//
#include <hip/hip_runtime.h>
#include <hip/hip_bf16.h>

#define VOCAB 50257
#define EMBED 128
#define BATCH 4096
#define CTX   8

#define BM 128
#define BN 64
#define LDSP 136   // padded LDS row stride in bf16 elements (136*2=272B, 272/4=68 dwords ≡ 4 mod 32 -> even bank spread)

typedef __attribute__((ext_vector_type(8))) short bf16x8;
typedef __attribute__((ext_vector_type(4))) float f32x4;

// ---------------- Kernel 1: embedding bag -> bf16 word_emb in ws ----------------
// One wave per batch row. lane handles 2 embed columns (float2 load, 8B/lane).
__global__ __launch_bounds__(256) void embed_bag_kernel(
    const int* __restrict__ idx, const float* __restrict__ Wp,
    __hip_bfloat16* __restrict__ emb) {
  int wave = threadIdx.x >> 6;
  int lane = threadIdx.x & 63;
  int row  = blockIdx.x * 4 + wave;          // [0, 4096)
  const int* ri = idx + row * CTX;
  int e0 = lane * 2;
  float s0 = 0.f, s1 = 0.f;
#pragma unroll
  for (int c = 0; c < CTX; ++c) {
    int w = ri[c];
    float2 wv = *reinterpret_cast<const float2*>(Wp + (size_t)w * EMBED + e0);
    s0 += wv.x; s1 += wv.y;
  }
  __hip_bfloat162 pv;
  pv.x = __float2bfloat16(s0);
  pv.y = __float2bfloat16(s1);
  *reinterpret_cast<__hip_bfloat162*>(emb + (size_t)row * EMBED + e0) = pv;
}

// ---------------- Kernel 2: [4096x128]bf16 @ [128x50257]f32->bf16 = [4096x50257]f32 ----------------
// Tile 128x64, 4 waves (each wave: 32 rows x 64 cols = 2x4 fragments of 16x16, K=128).
__global__ __launch_bounds__(256) void gemm_kernel(
    const __hip_bfloat16* __restrict__ A,   // ws word_emb [BATCH][EMBED]
    const float* __restrict__ Bm,           // W_pred [EMBED][VOCAB]
    float* __restrict__ C) {
  __shared__ ushort As[BM * LDSP];          // 34816 B
  __shared__ ushort Bs[BN * LDSP];          // 17408 B

  const int NXT = (VOCAB + BN - 1) / BN;    // 786 col tiles
  const int NYT = BATCH / BM;               // 32 row tiles
  // XCD-chunked swizzle: xcd k (= bid%8 under round-robin dispatch) owns col
  // strips x ≡ k (mod 8) for ALL row groups -> B slice (~3.2MB) stays L2-resident.
  int bid = blockIdx.x;
  int k8  = bid & 7;
  int j   = bid >> 3;
  int t   = j >> 5;                          // strip index within xcd
  int y   = j & 31;                          // row tile
  int x   = k8 + t * 8;                      // col tile
  if (x >= NXT) return;

  int tid = threadIdx.x;

  // ---- Stage A: 128 rows x 128 k, bf16, row-major padded ----
  const ushort* Ag = reinterpret_cast<const ushort*>(A) + (size_t)y * BM * EMBED;
#pragma unroll
  for (int i = 0; i < 8; ++i) {
    int c  = tid + i * 256;                  // 16B chunk id [0,2048)
    int r  = c >> 4;
    int k0 = (c & 15) << 3;
    uint4 v = *reinterpret_cast<const uint4*>(Ag + r * EMBED + k0);
    *reinterpret_cast<uint4*>(&As[r * LDSP + k0]) = v;
  }

  // ---- Stage B: transpose 128e x 64v fp32 -> Bs[v][e] bf16 ----
  {
    int v   = tid & 63;
    int col = x * BN + v;
    bool okc = (col < VOCAB);
    int ph  = tid >> 6;                      // 0..3
#pragma unroll
    for (int i = 0; i < 16; ++i) {
      int p = ph + i * 4;                    // e-pair index [0,64)
      int e = p * 2;
      float b0 = okc ? Bm[(size_t)e * VOCAB + col] : 0.f;
      float b1 = okc ? Bm[(size_t)(e + 1) * VOCAB + col] : 0.f;
      __hip_bfloat162 pv;
      pv.x = __float2bfloat16(b0);
      pv.y = __float2bfloat16(b1);
      *reinterpret_cast<__hip_bfloat162*>(&Bs[v * LDSP + e]) = pv;
    }
  }
  __syncthreads();

  // ---- MFMA: 2x4 fragments per wave, K loop of 4 ----
  int wv   = tid >> 6;
  int lane = tid & 63;
  int r0   = wv * 32;
  int lr   = lane & 15;                      // fragment row (A) / col (B)
  int lg   = lane >> 4;                      // k-group
  f32x4 acc[2][4] = {};
#pragma unroll
  for (int kk = 0; kk < EMBED; kk += 32) {
    int kb = kk + lg * 8;
    bf16x8 af[2], bfr[4];
#pragma unroll
    for (int m = 0; m < 2; ++m)
      af[m] = *reinterpret_cast<const bf16x8*>(&As[(r0 + m * 16 + lr) * LDSP + kb]);
#pragma unroll
    for (int n = 0; n < 4; ++n)
      bfr[n] = *reinterpret_cast<const bf16x8*>(&Bs[(n * 16 + lr) * LDSP + kb]);
#pragma unroll
    for (int m = 0; m < 2; ++m)
#pragma unroll
      for (int n = 0; n < 4; ++n)
        acc[m][n] = __builtin_amdgcn_mfma_f32_16x16x32_bf16(af[m], bfr[n], acc[m][n], 0, 0, 0);
  }

  // ---- Store: C/D layout col=lane&15, row=(lane>>4)*4+q ----
  size_t crow0 = (size_t)y * BM + r0;
  int cc0 = x * BN;
#pragma unroll
  for (int m = 0; m < 2; ++m) {
#pragma unroll
    for (int n = 0; n < 4; ++n) {
      int colc = cc0 + n * 16 + lr;
      if (colc < VOCAB) {
        float* cp = C + (crow0 + m * 16 + lg * 4) * (size_t)VOCAB + colc;
#pragma unroll
        for (int q = 0; q < 4; ++q)
          cp[(size_t)q * VOCAB] = acc[m][n][q];
      }
    }
  }
}

extern "C" void kernel_launch(void* const* d_in, const int* in_sizes, int n_in,
                              void* d_out, int out_size, void* d_ws, size_t ws_size,
                              hipStream_t stream) {
  const int*   idx    = (const int*)d_in[0];
  const float* W_proj = (const float*)d_in[1];
  const float* W_pred = (const float*)d_in[2];
  float*       out    = (float*)d_out;
  __hip_bfloat16* emb = (__hip_bfloat16*)d_ws;   // 4096*128*2 = 1 MB

  embed_bag_kernel<<<BATCH / 4, 256, 0, stream>>>(idx, W_proj, emb);

  const int NXT = (VOCAB + BN - 1) / BN;          // 786
  const int NYT = BATCH / BM;                     // 32
  int strips = (NXT + 7) / 8;                     // 99 strips per xcd
  int grid = 8 * strips * NYT;                    // 25344 (some return early)
  gemm_kernel<<<grid, 256, 0, stream>>>(emb, W_pred, out);
}

// Round 2
// 468.494 us; speedup vs baseline: 1.7532x; 1.7532x over previous
//
#include <hip/hip_runtime.h>
#include <hip/hip_bf16.h>

#define VOCAB 50257
#define EMBED 128
#define BATCH 4096
#define CTX   8

#define BM 128
#define BN 64
#define LDSP 132   // Bs row stride in bf16 elems (264B): read frags ~2-way banked

typedef __attribute__((ext_vector_type(8))) short bf16x8;
typedef __attribute__((ext_vector_type(4))) float f32x4;

static __device__ __forceinline__ ushort f2bf(float f) {
  __hip_bfloat16 h = __float2bfloat16(f);
  return *reinterpret_cast<ushort*>(&h);
}

// ---------------- Kernel 1: embedding bag -> bf16 word_emb in ws ----------------
__global__ __launch_bounds__(256) void embed_bag_kernel(
    const int* __restrict__ idx, const float* __restrict__ Wp,
    __hip_bfloat16* __restrict__ emb) {
  int wave = threadIdx.x >> 6;
  int lane = threadIdx.x & 63;
  int row  = blockIdx.x * 4 + wave;
  const int* ri = idx + row * CTX;
  int e0 = lane * 2;
  float s0 = 0.f, s1 = 0.f;
#pragma unroll
  for (int c = 0; c < CTX; ++c) {
    int w = ri[c];
    float2 wv = *reinterpret_cast<const float2*>(Wp + (size_t)w * EMBED + e0);
    s0 += wv.x; s1 += wv.y;
  }
  __hip_bfloat162 pv;
  pv.x = __float2bfloat16(s0);
  pv.y = __float2bfloat16(s1);
  *reinterpret_cast<__hip_bfloat162*>(emb + (size_t)row * EMBED + e0) = pv;
}

// ---------------- Kernel 2: GEMM [4096x128]bf16 @ [128x50257]f32 -> f32 ----------------
// 128x64 tile, 4 waves; A fragments loaded direct global->VGPR (L2-resident),
// B staged via 8 batched float4 loads -> bf16 transposed LDS (XOR-swizzled).
__global__ __launch_bounds__(256, 4) void gemm_kernel(
    const __hip_bfloat16* __restrict__ A,
    const float* __restrict__ Bm,
    float* __restrict__ C) {
  __shared__ char BsRaw[BN * LDSP * 2];   // 16896 B

  const int NXT = (VOCAB + BN - 1) / BN;  // 786
  int bid = blockIdx.x;
  int k8  = bid & 7;
  int j   = bid >> 3;
  int t   = j >> 5;
  int y   = j & 31;
  int x   = k8 + t * 8;                   // XCD-chunked col strip
  if (x >= NXT) return;

  int tid  = threadIdx.x;
  int lane = tid & 63;
  int wv   = tid >> 6;
  int lr   = lane & 15;
  int lg   = lane >> 4;
  int r0   = wv * 32;

  // ---- A fragments: 8 hoisted dwordx4, issued before B staging ----
  const ushort* Ag = reinterpret_cast<const ushort*>(A) + (size_t)(y * BM) * EMBED;
  uint4 a_raw[2][4];
#pragma unroll
  for (int m = 0; m < 2; ++m)
#pragma unroll
    for (int kq = 0; kq < 4; ++kq)
      a_raw[m][kq] = *reinterpret_cast<const uint4*>(
          Ag + (r0 + m * 16 + lr) * EMBED + kq * 32 + lg * 8);

  // ---- Stage B: batched loads (one vmcnt wait), then convert+transpose ----
  int cbase = x * BN;
  bool edge = (x == NXT - 1);
  float4 bb[8];
#pragma unroll
  for (int i = 0; i < 8; ++i) {
    int c  = tid + i * 256;               // [0,2048)
    int e  = c >> 4;                      // k-row 0..127
    int v4 = (c & 15) << 2;               // col offset 0..60
    int col = cbase + v4;
    if (!edge) {
      bb[i] = *reinterpret_cast<const float4*>(Bm + (size_t)e * VOCAB + col);
    } else {
      bb[i].x = (col + 0 < VOCAB) ? Bm[(size_t)e * VOCAB + col + 0] : 0.f;
      bb[i].y = (col + 1 < VOCAB) ? Bm[(size_t)e * VOCAB + col + 1] : 0.f;
      bb[i].z = (col + 2 < VOCAB) ? Bm[(size_t)e * VOCAB + col + 2] : 0.f;
      bb[i].w = (col + 3 < VOCAB) ? Bm[(size_t)e * VOCAB + col + 3] : 0.f;
    }
  }
#pragma unroll
  for (int i = 0; i < 8; ++i) {
    int c  = tid + i * 256;
    int e  = c >> 4;
    int v4 = (c & 15) << 2;
    float vals[4] = {bb[i].x, bb[i].y, bb[i].z, bb[i].w};
#pragma unroll
    for (int jj = 0; jj < 4; ++jj) {
      int v   = v4 + jj;
      int off = v * (LDSP * 2) + ((e * 2) ^ ((v & 28) << 2));  // XOR swizzle
      *reinterpret_cast<ushort*>(BsRaw + off) = f2bf(vals[jj]);
    }
  }
  __syncthreads();

  // ---- MFMA: 2x4 fragments, K=128 in 4 steps ----
  f32x4 acc[2][4] = {};
#pragma unroll
  for (int kq = 0; kq < 4; ++kq) {
    int ebyte = (kq * 32 + lg * 8) * 2;
    bf16x8 bfr[4];
#pragma unroll
    for (int n = 0; n < 4; ++n) {
      int v   = n * 16 + lr;
      int off = v * (LDSP * 2) + (ebyte ^ ((v & 28) << 2));
      bfr[n] = *reinterpret_cast<const bf16x8*>(BsRaw + off);
    }
#pragma unroll
    for (int m = 0; m < 2; ++m) {
      bf16x8 af = __builtin_bit_cast(bf16x8, a_raw[m][kq]);
#pragma unroll
      for (int n = 0; n < 4; ++n)
        acc[m][n] = __builtin_amdgcn_mfma_f32_16x16x32_bf16(af, bfr[n], acc[m][n], 0, 0, 0);
    }
  }

  // ---- Store: C/D layout col=lane&15, row=(lane>>4)*4+q ----
  size_t crow0 = (size_t)y * BM + r0;
  int cc0 = x * BN;
#pragma unroll
  for (int m = 0; m < 2; ++m) {
#pragma unroll
    for (int n = 0; n < 4; ++n) {
      int colc = cc0 + n * 16 + lr;
      if (colc < VOCAB) {
        float* cp = C + (crow0 + m * 16 + lg * 4) * (size_t)VOCAB + colc;
#pragma unroll
        for (int q = 0; q < 4; ++q)
          cp[(size_t)q * VOCAB] = acc[m][n][q];
      }
    }
  }
}

extern "C" void kernel_launch(void* const* d_in, const int* in_sizes, int n_in,
                              void* d_out, int out_size, void* d_ws, size_t ws_size,
                              hipStream_t stream) {
  const int*   idx    = (const int*)d_in[0];
  const float* W_proj = (const float*)d_in[1];
  const float* W_pred = (const float*)d_in[2];
  float*       out    = (float*)d_out;
  __hip_bfloat16* emb = (__hip_bfloat16*)d_ws;   // 1 MB

  embed_bag_kernel<<<BATCH / 4, 256, 0, stream>>>(idx, W_proj, emb);

  const int NXT = (VOCAB + BN - 1) / BN;          // 786
  int strips = (NXT + 7) / 8;                     // 99
  int grid = 8 * strips * 32;                     // 25344
  gemm_kernel<<<grid, 256, 0, stream>>>(emb, W_pred, out);
}

// Round 3
// 410.878 us; speedup vs baseline: 1.9991x; 1.1402x over previous
//
#include <hip/hip_runtime.h>
#include <hip/hip_bf16.h>

#define VOCAB 50257
#define EMBED 128
#define BATCH 4096
#define CTX   8

#define BM 128
#define BN 64
#define NXT 786            // col tiles of 64 (785*64+17 = 50257)
#define VPAD 50304         // 786*64, zero-padded Bt rows
#define LDSP 136           // transpose-stage LDS row stride (272B, 16B-aligned)

typedef __attribute__((ext_vector_type(8))) short bf16x8;
typedef __attribute__((ext_vector_type(4))) float f32x4;

static __device__ __forceinline__ ushort f2bf(float f) {
  __hip_bfloat16 h = __float2bfloat16(f);
  return *reinterpret_cast<ushort*>(&h);
}

// ---------------- Kernel 1: embedding bag -> bf16 word_emb ----------------
__global__ __launch_bounds__(256) void embed_bag_kernel(
    const int* __restrict__ idx, const float* __restrict__ Wp,
    __hip_bfloat16* __restrict__ emb) {
  int wave = threadIdx.x >> 6;
  int lane = threadIdx.x & 63;
  int row  = blockIdx.x * 4 + wave;
  const int* ri = idx + row * CTX;
  int e0 = lane * 2;
  float s0 = 0.f, s1 = 0.f;
#pragma unroll
  for (int c = 0; c < CTX; ++c) {
    int w = ri[c];
    float2 wv = *reinterpret_cast<const float2*>(Wp + (size_t)w * EMBED + e0);
    s0 += wv.x; s1 += wv.y;
  }
  __hip_bfloat162 pv;
  pv.x = __float2bfloat16(s0);
  pv.y = __float2bfloat16(s1);
  *reinterpret_cast<__hip_bfloat162*>(emb + (size_t)row * EMBED + e0) = pv;
}

// ---------------- Kernel 1b: W_pred [128][50257]f32 -> Bt [50304][128]bf16 ----------------
__global__ __launch_bounds__(256) void transpose_b_kernel(
    const float* __restrict__ Bm, ushort* __restrict__ Bt) {
  __shared__ ushort Bs[BN * LDSP];
  int x = blockIdx.x;
  int cbase = x * BN;
  int tid = threadIdx.x;
  bool edge = (cbase + BN > VOCAB);
#pragma unroll
  for (int i = 0; i < 8; ++i) {
    int c  = tid + i * 256;             // [0,2048)
    int e  = c >> 4;                    // k-row 0..127
    int v4 = (c & 15) << 2;             // col offset
    int col = cbase + v4;
    float4 b;
    if (!edge) {
      b = *reinterpret_cast<const float4*>(Bm + (size_t)e * VOCAB + col);
    } else {
      b.x = (col + 0 < VOCAB) ? Bm[(size_t)e * VOCAB + col + 0] : 0.f;
      b.y = (col + 1 < VOCAB) ? Bm[(size_t)e * VOCAB + col + 1] : 0.f;
      b.z = (col + 2 < VOCAB) ? Bm[(size_t)e * VOCAB + col + 2] : 0.f;
      b.w = (col + 3 < VOCAB) ? Bm[(size_t)e * VOCAB + col + 3] : 0.f;
    }
    Bs[(v4 + 0) * LDSP + e] = f2bf(b.x);
    Bs[(v4 + 1) * LDSP + e] = f2bf(b.y);
    Bs[(v4 + 2) * LDSP + e] = f2bf(b.z);
    Bs[(v4 + 3) * LDSP + e] = f2bf(b.w);
  }
  __syncthreads();
#pragma unroll
  for (int i = 0; i < 4; ++i) {
    int c = tid + i * 256;              // [0,1024)
    int v = c >> 4;
    int q = c & 15;                     // 8-elem chunk
    uint4 val = *reinterpret_cast<const uint4*>(&Bs[v * LDSP + q * 8]);
    *reinterpret_cast<uint4*>(Bt + (size_t)(cbase + v) * EMBED + q * 8) = val;
  }
}

// ---------------- Kernel 2: barrier-free GEMM via pre-transposed Bt ----------------
__global__ __launch_bounds__(256, 4) void gemm2_kernel(
    const ushort* __restrict__ A,       // emb bf16 [4096][128]
    const ushort* __restrict__ Bt,      // [50304][128] bf16
    float* __restrict__ C) {
  int bid = blockIdx.x;
  int k8  = bid & 7;
  int j   = bid >> 3;
  int t   = j >> 5;
  int y   = j & 31;
  int x   = k8 + t * 8;                 // XCD-chunked col strip
  if (x >= NXT) return;

  int tid  = threadIdx.x;
  int lane = tid & 63;
  int wv   = tid >> 6;
  int lr   = lane & 15;
  int lg   = lane >> 4;
  int r0   = wv * 32;

  // A fragments (L2-resident, 1 MB total)
  const ushort* Ag = A + (size_t)(y * BM) * EMBED;
  bf16x8 af[2][4];
#pragma unroll
  for (int m = 0; m < 2; ++m)
#pragma unroll
    for (int kq = 0; kq < 4; ++kq)
      af[m][kq] = *reinterpret_cast<const bf16x8*>(
          Ag + (r0 + m * 16 + lr) * EMBED + kq * 32 + lg * 8);

  int cc0 = x * BN;
  const ushort* Bg = Bt + (size_t)cc0 * EMBED + lg * 8;

  f32x4 acc[2][4] = {};
  bf16x8 bc[4], bn[4];
#pragma unroll
  for (int n = 0; n < 4; ++n)
    bc[n] = *reinterpret_cast<const bf16x8*>(Bg + (n * 16 + lr) * EMBED);
#pragma unroll
  for (int kq = 0; kq < 4; ++kq) {
    if (kq < 3) {
#pragma unroll
      for (int n = 0; n < 4; ++n)
        bn[n] = *reinterpret_cast<const bf16x8*>(
            Bg + (n * 16 + lr) * EMBED + (kq + 1) * 32);
    }
#pragma unroll
    for (int m = 0; m < 2; ++m)
#pragma unroll
      for (int n = 0; n < 4; ++n)
        acc[m][n] = __builtin_amdgcn_mfma_f32_16x16x32_bf16(af[m][kq], bc[n], acc[m][n], 0, 0, 0);
#pragma unroll
    for (int n = 0; n < 4; ++n) bc[n] = bn[n];
  }

  // Store: C/D layout col=lane&15, row=(lane>>4)*4+q
  size_t crow0 = (size_t)y * BM + r0;
#pragma unroll
  for (int m = 0; m < 2; ++m) {
#pragma unroll
    for (int n = 0; n < 4; ++n) {
      int colc = cc0 + n * 16 + lr;
      if (colc < VOCAB) {
        float* cp = C + (crow0 + m * 16 + lg * 4) * (size_t)VOCAB + colc;
#pragma unroll
        for (int q = 0; q < 4; ++q)
          cp[(size_t)q * VOCAB] = acc[m][n][q];
      }
    }
  }
}

// ---------------- Fallback GEMM (R2): LDS-staged, in case ws is small ----------------
#define FLDSP 132
__global__ __launch_bounds__(256, 4) void gemm_kernel(
    const __hip_bfloat16* __restrict__ A,
    const float* __restrict__ Bm,
    float* __restrict__ C) {
  __shared__ char BsRaw[BN * FLDSP * 2];
  int bid = blockIdx.x;
  int k8  = bid & 7;
  int j   = bid >> 3;
  int t   = j >> 5;
  int y   = j & 31;
  int x   = k8 + t * 8;
  if (x >= NXT) return;

  int tid  = threadIdx.x;
  int lane = tid & 63;
  int wv   = tid >> 6;
  int lr   = lane & 15;
  int lg   = lane >> 4;
  int r0   = wv * 32;

  const ushort* Ag = reinterpret_cast<const ushort*>(A) + (size_t)(y * BM) * EMBED;
  uint4 a_raw[2][4];
#pragma unroll
  for (int m = 0; m < 2; ++m)
#pragma unroll
    for (int kq = 0; kq < 4; ++kq)
      a_raw[m][kq] = *reinterpret_cast<const uint4*>(
          Ag + (r0 + m * 16 + lr) * EMBED + kq * 32 + lg * 8);

  int cbase = x * BN;
  bool edge = (x == NXT - 1);
  float4 bb[8];
#pragma unroll
  for (int i = 0; i < 8; ++i) {
    int c  = tid + i * 256;
    int e  = c >> 4;
    int v4 = (c & 15) << 2;
    int col = cbase + v4;
    if (!edge) {
      bb[i] = *reinterpret_cast<const float4*>(Bm + (size_t)e * VOCAB + col);
    } else {
      bb[i].x = (col + 0 < VOCAB) ? Bm[(size_t)e * VOCAB + col + 0] : 0.f;
      bb[i].y = (col + 1 < VOCAB) ? Bm[(size_t)e * VOCAB + col + 1] : 0.f;
      bb[i].z = (col + 2 < VOCAB) ? Bm[(size_t)e * VOCAB + col + 2] : 0.f;
      bb[i].w = (col + 3 < VOCAB) ? Bm[(size_t)e * VOCAB + col + 3] : 0.f;
    }
  }
#pragma unroll
  for (int i = 0; i < 8; ++i) {
    int c  = tid + i * 256;
    int e  = c >> 4;
    int v4 = (c & 15) << 2;
    float vals[4] = {bb[i].x, bb[i].y, bb[i].z, bb[i].w};
#pragma unroll
    for (int jj = 0; jj < 4; ++jj) {
      int v   = v4 + jj;
      int off = v * (FLDSP * 2) + ((e * 2) ^ ((v & 28) << 2));
      *reinterpret_cast<ushort*>(BsRaw + off) = f2bf(vals[jj]);
    }
  }
  __syncthreads();

  f32x4 acc[2][4] = {};
#pragma unroll
  for (int kq = 0; kq < 4; ++kq) {
    int ebyte = (kq * 32 + lg * 8) * 2;
    bf16x8 bfr[4];
#pragma unroll
    for (int n = 0; n < 4; ++n) {
      int v   = n * 16 + lr;
      int off = v * (FLDSP * 2) + (ebyte ^ ((v & 28) << 2));
      bfr[n] = *reinterpret_cast<const bf16x8*>(BsRaw + off);
    }
#pragma unroll
    for (int m = 0; m < 2; ++m) {
      bf16x8 af = __builtin_bit_cast(bf16x8, a_raw[m][kq]);
#pragma unroll
      for (int n = 0; n < 4; ++n)
        acc[m][n] = __builtin_amdgcn_mfma_f32_16x16x32_bf16(af, bfr[n], acc[m][n], 0, 0, 0);
    }
  }

  size_t crow0 = (size_t)y * BM + r0;
#pragma unroll
  for (int m = 0; m < 2; ++m) {
#pragma unroll
    for (int n = 0; n < 4; ++n) {
      int colc = cbase + n * 16 + lr;
      if (colc < VOCAB) {
        float* cp = C + (crow0 + m * 16 + lg * 4) * (size_t)VOCAB + colc;
#pragma unroll
        for (int q = 0; q < 4; ++q)
          cp[(size_t)q * VOCAB] = acc[m][n][q];
      }
    }
  }
}

extern "C" void kernel_launch(void* const* d_in, const int* in_sizes, int n_in,
                              void* d_out, int out_size, void* d_ws, size_t ws_size,
                              hipStream_t stream) {
  const int*   idx    = (const int*)d_in[0];
  const float* W_proj = (const float*)d_in[1];
  const float* W_pred = (const float*)d_in[2];
  float*       out    = (float*)d_out;

  __hip_bfloat16* emb = (__hip_bfloat16*)d_ws;                 // 1 MB
  ushort* Bt = (ushort*)((char*)d_ws + (size_t)1048576);       // 12.9 MB
  const size_t needed = (size_t)1048576 + (size_t)VPAD * EMBED * 2;

  embed_bag_kernel<<<BATCH / 4, 256, 0, stream>>>(idx, W_proj, emb);

  int strips = (NXT + 7) / 8;                  // 99
  int grid = 8 * strips * 32;                  // 25344

  if (ws_size >= needed) {
    transpose_b_kernel<<<NXT, 256, 0, stream>>>(W_pred, Bt);
    gemm2_kernel<<<grid, 256, 0, stream>>>(
        (const ushort*)emb, Bt, out);
  } else {
    gemm_kernel<<<grid, 256, 0, stream>>>(emb, W_pred, out);
  }
}